// Round 13
// baseline (852.430 us; speedup 1.0000x reference)
//
#include <hip/hip_runtime.h>
#include <hip/hip_bf16.h>

#define N_NODES 50000
#define N_EDGES 800000
#define IN_DIM 256
#define HID 32
#define HEADS 4
#define HO 128
#define EDGE_DIM 32
#define NG 32
#define OUT_DIM 128
#define SCALE 0.1767766952966369f       // 1/sqrt(32)
#define SCL2  0.2550889021232886f       // SCALE * log2(e)
#define NB_SCAN ((N_NODES + 255) / 256)   // 196
#define NB_NODE ((N_NODES + 63) / 64)     // 782
#define NB_CVT  312                        // ceil(TOTAL_W/256)

typedef unsigned short u16;
typedef unsigned int u32;

__device__ __forceinline__ float bf_lo(u32 w){ union{u32 i; float f;} c; c.i=w<<16; return c.f; }
__device__ __forceinline__ float bf_hi(u32 w){ union{u32 i; float f;} c; c.i=w&0xffff0000u; return c.f; }
__device__ __forceinline__ float bf2f(u16 u){ union{u32 i; float f;} c; c.i=((u32)u)<<16; return c.f; }
__device__ __forceinline__ u16 f2bf(float f){ u32 b = __float_as_uint(f); u32 r = (b + 0x7fffu + ((b>>16)&1u)) >> 16; return (u16)r; }
__device__ __forceinline__ void bf8_store(float* d, uint4 w){
  d[0]=bf_lo(w.x); d[1]=bf_hi(w.x); d[2]=bf_lo(w.y); d[3]=bf_hi(w.y);
  d[4]=bf_lo(w.z); d[5]=bf_hi(w.z); d[6]=bf_lo(w.w); d[7]=bf_hi(w.w);
}

// per-wave dtype flag: 1 = f32 inputs, 0 = bf16-pair inputs  (x is N(0,1))
__device__ __forceinline__ int wave_isf32(const u32* __restrict__ xw){
  u32 w = xw[threadIdx.x & 63];
  int e_hi = (w >> 23) & 0xFF;
  int e_lo = (w >> 7) & 0xFF;
  bool pair = (e_hi >= 110 && e_hi <= 140) && (e_lo >= 110 && e_lo <= 140);
  return (__popcll(__ballot(pair)) >= 32) ? 0 : 1;
}

// ---------------- weight blob offsets ----------------
#define OFF_WIN   0
#define OFF_BIN   8192
#define OFF_WEP   8224
#define OFF_BEP   9248
#define OFF_WQ    9280
#define OFF_BQ    21568
#define OFF_WK    21952
#define OFF_BK    34240
#define OFF_WV    34624
#define OFF_BV    46912
#define OFF_WE    47296
#define OFF_BE    59584
#define OFF_WO    59968
#define OFF_BO    72256
#define OFF_LNG   72352
#define OFF_LNB   72448
#define OFF_WO1   72544
#define OFF_BO1   75616
#define OFF_WO2   75648
#define OFF_BO2   79744
#define TOTAL_W   79872

struct Ptrs { const void* p[20]; };

// ---------------- fused: weight convert (blocks 0..311) + edge-weight fold (blocks 312..314) ----------------
__global__ __launch_bounds__(256) void k_prep(Ptrs P, const u32* __restrict__ xw,
                                              float* __restrict__ blob,
                                              float* __restrict__ M2T, float* __restrict__ bvecb){
  int isf32 = wave_isf32(xw);
  int b = blockIdx.x;
  if (b < NB_CVT){
    const int offs[21] = {OFF_WIN,OFF_BIN,OFF_WEP,OFF_BEP,OFF_WQ,OFF_BQ,OFF_WK,OFF_BK,
                          OFF_WV,OFF_BV,OFF_WE,OFF_BE,OFF_WO,OFF_BO,OFF_LNG,OFF_LNB,
                          OFF_WO1,OFF_BO1,OFF_WO2,OFF_BO2,TOTAL_W};
    int i = b*256 + threadIdx.x;
    if (i >= TOTAL_W) return;
    int t = 0;
    while (i >= offs[t+1]) ++t;
    int j = i - offs[t];
    blob[i] = isf32 ? ((const float*)P.p[t])[j] : bf2f(((const u16*)P.p[t])[j]);
  } else {
    int l = b - NB_CVT;
    const void* We  = P.p[10];
    const void* Wep = P.p[2];
    const void* be  = P.p[11];
    const void* bep = P.p[3];
    auto ld = [&](const void* q2, int idx)->float{
      return isf32 ? ((const float*)q2)[idx] : bf2f(((const u16*)q2)[idx]);
    };
    int t = threadIdx.x;
    for (int e = t; e < 4096; e += 256){
      int d = e >> 7, o = e & 127;
      int j = o & 31, hh = o >> 5;
      float s = 0.f;
      #pragma unroll
      for (int c=0; c<32; ++c) s += ld(Wep, j*32 + c) * ld(We, l*HID*HO + c*HO + hh*32 + d);
      M2T[l*4096 + e] = s;
    }
    if (t < HO){
      float s = ld(be, l*HO + t);
      #pragma unroll
      for (int c=0; c<32; ++c) s += ld(bep, c) * ld(We, l*HID*HO + c*HO + t);
      bvecb[l*HO + t] = s;
    }
  }
}

// ---------------- CSR build ----------------
__global__ void k_deg(const int* __restrict__ ei, int* __restrict__ deg){
  int e = blockIdx.x*256 + threadIdx.x;
  atomicAdd(&deg[ei[N_EDGES + e]], 1);
}

// block scan over deg + group histogram (same node range)  [G12]
__global__ __launch_bounds__(256) void k_scan_a(const int* __restrict__ deg, int* __restrict__ off,
                                                int* __restrict__ bsum,
                                                const int* __restrict__ batch, int* __restrict__ gcount){
  __shared__ int wsum[4];
  __shared__ int hist[NG];
  int tid = threadIdx.x;
  if (tid < NG) hist[tid] = 0;
  int i = blockIdx.x*256 + tid;
  int d = (i < N_NODES) ? deg[i] : 0;
  int lane = tid & 63, w = tid >> 6;
  int incl = d;
  #pragma unroll
  for (int sh=1; sh<64; sh<<=1){
    int t = __shfl_up(incl, sh, 64);
    if (lane >= sh) incl += t;
  }
  if (lane == 63) wsum[w] = incl;
  __syncthreads();     // wsum ready, hist zeroed
  int wpre = 0;
  #pragma unroll
  for (int ww=0; ww<4; ++ww) wpre += (ww < w) ? wsum[ww] : 0;
  if (i < N_NODES) off[i] = wpre + incl - d;
  if (tid == 255) bsum[blockIdx.x] = wpre + incl;
  if (i < N_NODES) atomicAdd(&hist[batch[i]], 1);
  __syncthreads();
  if (tid < NG){
    int c = hist[tid];
    if (c) atomicAdd(&gcount[tid], c);
  }
}

__global__ void k_scan_b(const int* __restrict__ bsum, int* __restrict__ bpre, int* __restrict__ off){
  int lane = threadIdx.x;    // 64
  int carry = 0;
  for (int base=0; base<NB_SCAN; base+=64){
    int i = base + lane;
    int d = (i<NB_SCAN)? bsum[i] : 0;
    int incl = d;
    #pragma unroll
    for (int sh=1; sh<64; sh<<=1){
      int t = __shfl_up(incl, sh, 64);
      if (lane >= sh) incl += t;
    }
    if (i<NB_SCAN) bpre[i] = carry + incl - d;
    carry += __shfl(incl, 63, 64);
  }
  if (lane==0) off[N_NODES] = carry;
}

__global__ __launch_bounds__(256) void k_scan_c(int* __restrict__ off, const int* __restrict__ bpre){
  int i = blockIdx.x*256 + threadIdx.x;
  if (i < N_NODES) off[i] += bpre[blockIdx.x];
}

// slot computation; srcs + inverse permutation einv (both L2-resident scatters)
__global__ void k_fill(const int* __restrict__ ei, const int* __restrict__ off,
                       int* __restrict__ cursor, int* __restrict__ srcs, int* __restrict__ einv){
  int e = blockIdx.x*256 + threadIdx.x;
  int dst = ei[N_EDGES + e];
  int pos = atomicAdd(&cursor[dst], 1);
  int sl = off[dst] + pos;
  srcs[sl] = ei[e];
  einv[sl] = e;
}

// permute eattr into CSR order (gather by slot): random 128B-line reads, streaming writes
__global__ __launch_bounds__(256) void k_eperm(const int* __restrict__ einv, const void* __restrict__ eattr,
                                               const u32* __restrict__ xw, u32* __restrict__ ebf){
  int isf32 = wave_isf32(xw);
  int tid = blockIdx.x*256 + threadIdx.x;   // over N_EDGES*16
  int s = tid >> 4, j = tid & 15;
  int e = einv[s];
  u32 w;
  if (isf32){
    float2 v2 = reinterpret_cast<const float2*>(eattr)[(size_t)e*16 + j];
    w = (u32)f2bf(v2.x) | ((u32)f2bf(v2.y) << 16);
  } else {
    w = reinterpret_cast<const u32*>(eattr)[(size_t)e*16 + j];
  }
  ebf[(size_t)s*16 + j] = w;
}

// ---------------- h = x @ W_in + b_in ----------------
__global__ __launch_bounds__(256) void k_embed(const void* __restrict__ xraw,
                                               const float* __restrict__ Wb, const float* __restrict__ bb,
                                               float* __restrict__ h){
  __shared__ float xs[8*IN_DIM];
  __shared__ float wsm[IN_DIM*HID];
  int isf32 = wave_isf32((const u32*)xraw);
  int tid = threadIdx.x;
  const float4* wp = reinterpret_cast<const float4*>(Wb);
  #pragma unroll
  for (int it=0; it<8; ++it) ((float4*)wsm)[it*256 + tid] = wp[it*256 + tid];
  if (isf32){
    const float4* xp = reinterpret_cast<const float4*>((const float*)xraw + (size_t)blockIdx.x*8*IN_DIM);
    ((float4*)xs)[tid]       = xp[tid];
    ((float4*)xs)[256 + tid] = xp[256 + tid];
  } else {
    const uint4* xp = reinterpret_cast<const uint4*>((const u16*)xraw + (size_t)blockIdx.x*8*IN_DIM);
    bf8_store(&xs[tid*8], xp[tid]);
  }
  __syncthreads();
  int nl = tid >> 5, j = tid & 31;
  float acc = bb[j];
  const float* xr = &xs[nl*IN_DIM];
  #pragma unroll 8
  for (int c=0; c<IN_DIM; ++c) acc += xr[c]*wsm[c*HID + j];
  h[(size_t)(blockIdx.x*8 + nl)*HID + j] = acc;
}

// ---------------- fused q,k,v + uw + bias4 (q stays in LDS); k,v interleaved per node ----------------
// kv[n*128 + L] = k-pair word; kv[n*128 + 64 + L] = v-pair word.
__global__ __launch_bounds__(384) void k_qkvuw2(const float* __restrict__ h,
    const float* __restrict__ blob, const float* __restrict__ M2T,
    const float* __restrict__ bvecb, int l,
    float* __restrict__ q, u32* __restrict__ kv,
    float* __restrict__ uw, float* __restrict__ bias4){
  __shared__ float qs[64*HO];     // 32 KB
  int tid = threadIdx.x;
  int w = tid >> 6, lane = tid & 63;
  int hh = lane >> 4, t = lane & 15;
  int c0 = hh*32 + 2*t;
  int c1 = c0 + 1;
  {
    int m = w >> 1, half = w & 1;
    const float* Wm = blob + (m==0 ? OFF_WQ : m==1 ? OFF_WK : OFF_WV) + l*HID*HO;
    const float* bm = blob + (m==0 ? OFF_BQ : m==1 ? OFF_BK : OFF_BV) + l*HO;
    float wA[HID], wB[HID];
    #pragma unroll
    for (int c=0; c<HID; ++c){ wA[c] = Wm[c*HO + c0]; wB[c] = Wm[c*HO + c1]; }
    float bA = bm[c0], bB = bm[c1];
    int voff = (m==1) ? 0 : 64;
    int n0 = blockIdx.x*64 + half*32;
    int nend = n0 + 32; if (nend > N_NODES) nend = N_NODES;
    #pragma unroll 2
    for (int n=n0; n<nend; ++n){
      const float4* hp = reinterpret_cast<const float4*>(h + (size_t)n*HID);
      float accA = bA, accB = bB;
      #pragma unroll
      for (int c4=0; c4<8; ++c4){
        float4 hv = hp[c4];
        accA += hv.x*wA[c4*4+0] + hv.y*wA[c4*4+1] + hv.z*wA[c4*4+2] + hv.w*wA[c4*4+3];
        accB += hv.x*wB[c4*4+0] + hv.y*wB[c4*4+1] + hv.z*wB[c4*4+2] + hv.w*wB[c4*4+3];
      }
      if (m==0){
        *reinterpret_cast<float2*>(q + (size_t)n*HO + c0) = make_float2(accA, accB);
        int loc = half*32 + (n - n0);
        qs[loc*HO + c0] = accA;
        qs[loc*HO + c1] = accB;
      } else {
        kv[(size_t)n*128 + voff + lane] = (u32)f2bf(accA) | ((u32)f2bf(accB) << 16);
      }
    }
  }
  __syncthreads();
  {
    const float* M2l = M2T + l*4096;
    float m2A[HID], m2B[HID];
    #pragma unroll
    for (int d=0; d<HID; ++d){
      m2A[d] = M2l[d*HO + c0];
      m2B[d] = M2l[d*HO + c1];
    }
    float bv0 = bvecb[l*HO + c0], bv1 = bvecb[l*HO + c1];
    int nbase = blockIdx.x*64;
    for (int i = w; i < 64; i += 6){
      int n = nbase + i;
      if (n >= N_NODES) break;
      const float* qrow = &qs[i*HO];
      const float4* qh = reinterpret_cast<const float4*>(qrow + hh*32);
      float a0 = 0.f, a1 = 0.f;
      #pragma unroll
      for (int c4=0; c4<8; ++c4){
        float4 v = qh[c4];
        a0 += v.x*m2A[c4*4+0] + v.y*m2A[c4*4+1] + v.z*m2A[c4*4+2] + v.w*m2A[c4*4+3];
        a1 += v.x*m2B[c4*4+0] + v.y*m2B[c4*4+1] + v.z*m2B[c4*4+2] + v.w*m2B[c4*4+3];
      }
      float pb = qrow[c0]*bv0 + qrow[c1]*bv1;
      pb += __shfl_xor(pb, 1);
      pb += __shfl_xor(pb, 2);
      pb += __shfl_xor(pb, 4);
      pb += __shfl_xor(pb, 8);
      *reinterpret_cast<float2*>(uw + (size_t)n*HO + c0) = make_float2(a0, a1);
      if (t == 0) bias4[(size_t)n*HEADS + hh] = pb;
    }
  }
}

// ---------------- fused: alpha + softmax(heads) + aggregate + Wo + residual + LN ----------------
// 8/4/1-edge unrolled gather loop; kv interleaved (one 512B record per src node).
__global__ __launch_bounds__(256) void k_attn_agg(const int* __restrict__ off,
    const int* __restrict__ srcs,
    const float* __restrict__ q, const u32* __restrict__ kv,
    const float* __restrict__ uw, const float* __restrict__ bias4,
    const u32* __restrict__ ebf,
    const float* __restrict__ Wo, const float* __restrict__ bo,
    const float* __restrict__ lng, const float* __restrict__ lnb,
    int l, int last, float* __restrict__ h, float* __restrict__ hout){
  __shared__ float aggs[4][HO];
  int tid = threadIdx.x;
  int wv = tid >> 6;          // wave -> node
  int L  = tid & 63;
  int n = blockIdx.x*4 + wv;
  int hh = L >> 4, t = L & 15;
  int c0 = hh*32 + 2*t;
  int s0 = off[n], s1 = off[n+1];
  float2 qp = *reinterpret_cast<const float2*>(q  + (size_t)n*HO + c0);
  float2 wp = *reinterpret_cast<const float2*>(uw + (size_t)n*HO + c0);
  float4 B = reinterpret_cast<const float4*>(bias4)[n];
  float bg = (hh==0)? B.x : (hh==1)? B.y : (hh==2)? B.z : B.w;
  float acc0=0.f, acc1=0.f;
  auto proc = [&](u32 kw, u32 vw, u32 ew){
    float pa = qp.x*bf_lo(kw) + qp.y*bf_hi(kw) + wp.x*bf_lo(ew) + wp.y*bf_hi(ew);
    pa += __shfl_xor(pa, 1);
    pa += __shfl_xor(pa, 2);
    pa += __shfl_xor(pa, 4);
    pa += __shfl_xor(pa, 8);
    float e = exp2f((pa + bg)*SCL2);
    float ssum = e + __shfl_xor(e, 16);
    ssum += __shfl_xor(ssum, 32);
    float wgt = e * __builtin_amdgcn_rcpf(ssum);
    acc0 += bf_lo(vw)*wgt;
    acc1 += bf_hi(vw)*wgt;
  };
  int s = s0;
  for (; s + 8 <= s1; s += 8){
    int sn[8];
    u32 kw[8], vw[8], ew[8];
    #pragma unroll
    for (int u=0; u<8; ++u) sn[u] = srcs[s+u];
    #pragma unroll
    for (int u=0; u<8; ++u){
      const u32* base = kv + (size_t)sn[u]*128;
      kw[u] = base[L];
      vw[u] = base[64 + L];
      ew[u] = ebf[(size_t)(s+u)*16 + t];
    }
    #pragma unroll
    for (int u=0; u<8; ++u) proc(kw[u], vw[u], ew[u]);
  }
  if (s + 4 <= s1){
    int sn[4];
    u32 kw[4], vw[4], ew[4];
    #pragma unroll
    for (int u=0; u<4; ++u) sn[u] = srcs[s+u];
    #pragma unroll
    for (int u=0; u<4; ++u){
      const u32* base = kv + (size_t)sn[u]*128;
      kw[u] = base[L];
      vw[u] = base[64 + L];
      ew[u] = ebf[(size_t)(s+u)*16 + t];
    }
    #pragma unroll
    for (int u=0; u<4; ++u) proc(kw[u], vw[u], ew[u]);
    s += 4;
  }
  for (; s < s1; ++s){
    int sn = srcs[s];
    const u32* base = kv + (size_t)sn*128;
    proc(base[L], base[64 + L], ebf[(size_t)s*16 + t]);
  }
  *reinterpret_cast<float2*>(&aggs[wv][c0]) = make_float2(acc0, acc1);
  __syncthreads();
  if (tid < 128){
    int nl2 = tid >> 5, j = tid & 31;
    int nn = blockIdx.x*4 + nl2;
    const float* Wol = Wo + l*HO*HID;
    float o = bo[l*HID + j];
    #pragma unroll
    for (int i=0; i<HO; ++i) o += aggs[nl2][i] * Wol[i*HID + j];
    o += h[(size_t)nn*HID + j];                       // residual
    float sum = o;
    #pragma unroll
    for (int m=16; m>=1; m>>=1) sum += __shfl_xor(sum, m);
    float mu = sum * (1.f/32.f);
    float dv = o - mu;
    float vs = dv*dv;
    #pragma unroll
    for (int m=16; m>=1; m>>=1) vs += __shfl_xor(vs, m);
    float xn = dv * rsqrtf(vs*(1.f/32.f) + 1e-5f);
    float res = xn * lng[l*HID + j] + lnb[l*HID + j];
    h[(size_t)nn*HID + j] = res;
    if (last) hout[(size_t)nn*HID + j] = res;
  }
}

// ---------------- pooling (one block per graph; computes own gstart prefix) ----------------
__global__ __launch_bounds__(256) void k_pool(const float* __restrict__ h,
                                              const int* __restrict__ gcount, float* __restrict__ pools){
  __shared__ int gc[NG];
  int g = blockIdx.x;
  int tid = threadIdx.x;
  if (tid < NG) gc[tid] = gcount[tid];
  __syncthreads();
  int start = 0;
  for (int g2=0; g2<g; ++g2) start += gc[g2];
  int cnt = gc[g];
  int sub = tid >> 5, j = tid & 31;
  float sum = 0.f, mx = -1e30f, gs = 0.f;
  for (int i = start + sub; i < start + cnt; i += 8){
    float val = h[(size_t)i*HID + j];
    sum += val;
    mx = fmaxf(mx, val);
    gs += val * (1.0f/(1.0f + __expf(-val)));
  }
  __shared__ float ls[8][HID], lm[8][HID], lg[8][HID];
  ls[sub][j]=sum; lm[sub][j]=mx; lg[sub][j]=gs;
  __syncthreads();
  if (tid < HID){
    float S=0.f, M=-1e30f, G=0.f;
    #pragma unroll
    for (int s2=0; s2<8; ++s2){ S+=ls[s2][tid]; M=fmaxf(M,lm[s2][tid]); G+=lg[s2][tid]; }
    float c = (float)((cnt>0)?cnt:1);
    pools[g*96 + tid]      = S/c;
    pools[g*96 + 32 + tid] = M;
    pools[g*96 + 64 + tid] = G/c;
  }
}

// ---------------- head MLP ----------------
__global__ __launch_bounds__(128) void k_head(const float* __restrict__ pools,
    const float* __restrict__ Wo1, const float* __restrict__ bo1,
    const float* __restrict__ Wo2, const float* __restrict__ bo2,
    float* __restrict__ out){
  int g = blockIdx.x, tid = threadIdx.x;
  __shared__ float rep[96], hid[HID];
  if (tid < 96) rep[tid] = pools[g*96 + tid];
  __syncthreads();
  if (tid < HID){
    float s = bo1[tid];
    #pragma unroll
    for (int c=0; c<96; ++c) s += rep[c]*Wo1[c*HID + tid];
    hid[tid] = fmaxf(s, 0.0f);
  }
  __syncthreads();
  float s = bo2[tid];
  #pragma unroll
  for (int j2=0; j2<HID; ++j2) s += hid[j2]*Wo2[j2*OUT_DIM + tid];
  out[g*OUT_DIM + tid] = s;
}

// ---------------- host ----------------
extern "C" void kernel_launch(void* const* d_in, const int* in_sizes, int n_in,
                              void* d_out, int out_size, void* d_ws, size_t ws_size,
                              hipStream_t stream){
  const void* x     = d_in[0];
  const int*  ei    = (const int*)d_in[1];
  const void* eattr = d_in[2];
  const int*  batch = (const int*)d_in[3];
  float* out = (float*)d_out;

  char* p = (char*)d_ws;
  auto take = [&](size_t bytes)->char*{ char* r = p; p += (bytes + 255) & ~(size_t)255; return r; };
  float* h     = (float*)take((size_t)N_NODES*HID*4);
  float* q     = (float*)take((size_t)N_NODES*HO*4);
  u32*   kv    = (u32*)  take((size_t)N_NODES*128*4);
  float* uw    = (float*)take((size_t)N_NODES*HO*4);
  float* bias4 = (float*)take((size_t)N_NODES*HEADS*4);
  // zeroed block: deg | cursor | gcount (single memset)
  char* zbase  = take((size_t)N_NODES*4 + 256 + (size_t)N_NODES*4 + 256 + NG*4);
  int* deg     = (int*)zbase;
  int* cursor  = (int*)(zbase + (((size_t)N_NODES*4 + 255) & ~(size_t)255));
  int* gcount  = (int*)((char*)cursor + (((size_t)N_NODES*4 + 255) & ~(size_t)255));
  size_t zspan = ((char*)gcount + NG*4) - zbase;
  int* off     = (int*)take((size_t)(N_NODES+1)*4);
  int* srcs    = (int*)take((size_t)N_EDGES*4);
  int* einv    = (int*)take((size_t)N_EDGES*4);
  float* pools = (float*)take(NG*96*4);
  int*   bsum  = (int*)take(NB_SCAN*4);
  int*   bpre  = (int*)take(NB_SCAN*4);
  float* blob  = (float*)take((size_t)TOTAL_W*4);
  float* M2T   = (float*)take((size_t)3*4096*4);
  float* bvecb = (float*)take((size_t)3*HO*4);
  u32*   ebf   = (u32*)  take((size_t)N_EDGES*16*4);
  (void)ws_size; (void)in_sizes; (void)n_in; (void)out_size;

  Ptrs P;
  for (int i=0; i<20; ++i) P.p[i] = d_in[4+i];

  k_prep<<<NB_CVT + 3, 256, 0, stream>>>(P, (const u32*)x, blob, M2T, bvecb);
  hipMemsetAsync(zbase, 0, zspan, stream);
  k_deg <<<N_EDGES/256, 256, 0, stream>>>(ei, deg);
  k_scan_a<<<NB_SCAN, 256, 0, stream>>>(deg, off, bsum, batch, gcount);
  k_scan_b<<<1, 64, 0, stream>>>(bsum, bpre, off);
  k_scan_c<<<NB_SCAN, 256, 0, stream>>>(off, bpre);
  k_fill<<<N_EDGES/256, 256, 0, stream>>>(ei, off, cursor, srcs, einv);
  k_eperm<<<(N_EDGES*16)/256, 256, 0, stream>>>(einv, eattr, (const u32*)x, ebf);
  k_embed<<<N_NODES/8, 256, 0, stream>>>(x, blob+OFF_WIN, blob+OFF_BIN, h);
  for (int l=0; l<3; ++l){
    k_qkvuw2<<<NB_NODE, 384, 0, stream>>>(h, blob, M2T, bvecb, l, q, kv, uw, bias4);
    k_attn_agg<<<N_NODES/4, 256, 0, stream>>>(off, srcs, q, kv, uw, bias4, ebf,
                                              blob+OFF_WO, blob+OFF_BO, blob+OFF_LNG, blob+OFF_LNB,
                                              l, (l==2)?1:0, h, out + NG*OUT_DIM);
  }
  k_pool<<<NG, 256, 0, stream>>>(h, gcount, pools);
  k_head<<<NG, 128, 0, stream>>>(pools, blob+OFF_WO1, blob+OFF_BO1, blob+OFF_WO2, blob+OFF_BO2, out);
}

// Round 14
// 829.498 us; speedup vs baseline: 1.0276x; 1.0276x over previous
//
#include <hip/hip_runtime.h>
#include <hip/hip_bf16.h>

#define N_NODES 50000
#define N_EDGES 800000
#define IN_DIM 256
#define HID 32
#define HEADS 4
#define HO 128
#define EDGE_DIM 32
#define NG 32
#define OUT_DIM 128
#define SCALE 0.1767766952966369f       // 1/sqrt(32)
#define SCL2  0.2550889021232886f       // SCALE * log2(e)
#define NB_SCAN ((N_NODES + 255) / 256)   // 196
#define NB_NODE ((N_NODES + 63) / 64)     // 782
#define NB_CVT  312                        // ceil(TOTAL_W/256)

typedef unsigned short u16;
typedef unsigned int u32;

__device__ __forceinline__ float bf_lo(u32 w){ union{u32 i; float f;} c; c.i=w<<16; return c.f; }
__device__ __forceinline__ float bf_hi(u32 w){ union{u32 i; float f;} c; c.i=w&0xffff0000u; return c.f; }
__device__ __forceinline__ float bf2f(u16 u){ union{u32 i; float f;} c; c.i=((u32)u)<<16; return c.f; }
__device__ __forceinline__ u16 f2bf(float f){ u32 b = __float_as_uint(f); u32 r = (b + 0x7fffu + ((b>>16)&1u)) >> 16; return (u16)r; }
__device__ __forceinline__ void bf8_store(float* d, uint4 w){
  d[0]=bf_lo(w.x); d[1]=bf_hi(w.x); d[2]=bf_lo(w.y); d[3]=bf_hi(w.y);
  d[4]=bf_lo(w.z); d[5]=bf_hi(w.z); d[6]=bf_lo(w.w); d[7]=bf_hi(w.w);
}

// per-wave dtype flag: 1 = f32 inputs, 0 = bf16-pair inputs  (x is N(0,1))
__device__ __forceinline__ int wave_isf32(const u32* __restrict__ xw){
  u32 w = xw[threadIdx.x & 63];
  int e_hi = (w >> 23) & 0xFF;
  int e_lo = (w >> 7) & 0xFF;
  bool pair = (e_hi >= 110 && e_hi <= 140) && (e_lo >= 110 && e_lo <= 140);
  return (__popcll(__ballot(pair)) >= 32) ? 0 : 1;
}

// ---------------- weight blob offsets ----------------
#define OFF_WIN   0
#define OFF_BIN   8192
#define OFF_WEP   8224
#define OFF_BEP   9248
#define OFF_WQ    9280
#define OFF_BQ    21568
#define OFF_WK    21952
#define OFF_BK    34240
#define OFF_WV    34624
#define OFF_BV    46912
#define OFF_WE    47296
#define OFF_BE    59584
#define OFF_WO    59968
#define OFF_BO    72256
#define OFF_LNG   72352
#define OFF_LNB   72448
#define OFF_WO1   72544
#define OFF_BO1   75616
#define OFF_WO2   75648
#define OFF_BO2   79744
#define TOTAL_W   79872

struct Ptrs { const void* p[20]; };

// ---------------- fused: weight convert (blocks 0..311) + edge-weight fold (blocks 312..314) ----------------
__global__ __launch_bounds__(256) void k_prep(Ptrs P, const u32* __restrict__ xw,
                                              float* __restrict__ blob,
                                              float* __restrict__ M2T, float* __restrict__ bvecb){
  int isf32 = wave_isf32(xw);
  int b = blockIdx.x;
  if (b < NB_CVT){
    const int offs[21] = {OFF_WIN,OFF_BIN,OFF_WEP,OFF_BEP,OFF_WQ,OFF_BQ,OFF_WK,OFF_BK,
                          OFF_WV,OFF_BV,OFF_WE,OFF_BE,OFF_WO,OFF_BO,OFF_LNG,OFF_LNB,
                          OFF_WO1,OFF_BO1,OFF_WO2,OFF_BO2,TOTAL_W};
    int i = b*256 + threadIdx.x;
    if (i >= TOTAL_W) return;
    int t = 0;
    while (i >= offs[t+1]) ++t;
    int j = i - offs[t];
    blob[i] = isf32 ? ((const float*)P.p[t])[j] : bf2f(((const u16*)P.p[t])[j]);
  } else {
    int l = b - NB_CVT;
    const void* We  = P.p[10];
    const void* Wep = P.p[2];
    const void* be  = P.p[11];
    const void* bep = P.p[3];
    auto ld = [&](const void* q2, int idx)->float{
      return isf32 ? ((const float*)q2)[idx] : bf2f(((const u16*)q2)[idx]);
    };
    int t = threadIdx.x;
    for (int e = t; e < 4096; e += 256){
      int d = e >> 7, o = e & 127;
      int j = o & 31, hh = o >> 5;
      float s = 0.f;
      #pragma unroll
      for (int c=0; c<32; ++c) s += ld(Wep, j*32 + c) * ld(We, l*HID*HO + c*HO + hh*32 + d);
      M2T[l*4096 + e] = s;
    }
    if (t < HO){
      float s = ld(be, l*HO + t);
      #pragma unroll
      for (int c=0; c<32; ++c) s += ld(bep, c) * ld(We, l*HID*HO + c*HO + t);
      bvecb[l*HO + t] = s;
    }
  }
}

// ---------------- CSR build ----------------
__global__ void k_deg(const int* __restrict__ ei, int* __restrict__ deg){
  int e = blockIdx.x*256 + threadIdx.x;
  atomicAdd(&deg[ei[N_EDGES + e]], 1);
}

// block scan over deg + group histogram (same node range)  [G12]
__global__ __launch_bounds__(256) void k_scan_a(const int* __restrict__ deg, int* __restrict__ off,
                                                int* __restrict__ bsum,
                                                const int* __restrict__ batch, int* __restrict__ gcount){
  __shared__ int wsum[4];
  __shared__ int hist[NG];
  int tid = threadIdx.x;
  if (tid < NG) hist[tid] = 0;
  int i = blockIdx.x*256 + tid;
  int d = (i < N_NODES) ? deg[i] : 0;
  int lane = tid & 63, w = tid >> 6;
  int incl = d;
  #pragma unroll
  for (int sh=1; sh<64; sh<<=1){
    int t = __shfl_up(incl, sh, 64);
    if (lane >= sh) incl += t;
  }
  if (lane == 63) wsum[w] = incl;
  __syncthreads();     // wsum ready, hist zeroed
  int wpre = 0;
  #pragma unroll
  for (int ww=0; ww<4; ++ww) wpre += (ww < w) ? wsum[ww] : 0;
  if (i < N_NODES) off[i] = wpre + incl - d;
  if (tid == 255) bsum[blockIdx.x] = wpre + incl;
  if (i < N_NODES) atomicAdd(&hist[batch[i]], 1);
  __syncthreads();
  if (tid < NG){
    int c = hist[tid];
    if (c) atomicAdd(&gcount[tid], c);
  }
}

__global__ void k_scan_b(const int* __restrict__ bsum, int* __restrict__ bpre, int* __restrict__ off){
  int lane = threadIdx.x;    // 64
  int carry = 0;
  for (int base=0; base<NB_SCAN; base+=64){
    int i = base + lane;
    int d = (i<NB_SCAN)? bsum[i] : 0;
    int incl = d;
    #pragma unroll
    for (int sh=1; sh<64; sh<<=1){
      int t = __shfl_up(incl, sh, 64);
      if (lane >= sh) incl += t;
    }
    if (i<NB_SCAN) bpre[i] = carry + incl - d;
    carry += __shfl(incl, 63, 64);
  }
  if (lane==0) off[N_NODES] = carry;
}

__global__ __launch_bounds__(256) void k_scan_c(int* __restrict__ off, const int* __restrict__ bpre){
  int i = blockIdx.x*256 + threadIdx.x;
  if (i < N_NODES) off[i] += bpre[blockIdx.x];
}

// slot computation; srcs + inverse permutation einv (both L2-resident scatters)
__global__ void k_fill(const int* __restrict__ ei, const int* __restrict__ off,
                       int* __restrict__ cursor, int* __restrict__ srcs, int* __restrict__ einv){
  int e = blockIdx.x*256 + threadIdx.x;
  int dst = ei[N_EDGES + e];
  int pos = atomicAdd(&cursor[dst], 1);
  int sl = off[dst] + pos;
  srcs[sl] = ei[e];
  einv[sl] = e;
}

// permute eattr into CSR order (gather by slot): random 128B-line reads, streaming writes
__global__ __launch_bounds__(256) void k_eperm(const int* __restrict__ einv, const void* __restrict__ eattr,
                                               const u32* __restrict__ xw, u32* __restrict__ ebf){
  int isf32 = wave_isf32(xw);
  int tid = blockIdx.x*256 + threadIdx.x;   // over N_EDGES*16
  int s = tid >> 4, j = tid & 15;
  int e = einv[s];
  u32 w;
  if (isf32){
    float2 v2 = reinterpret_cast<const float2*>(eattr)[(size_t)e*16 + j];
    w = (u32)f2bf(v2.x) | ((u32)f2bf(v2.y) << 16);
  } else {
    w = reinterpret_cast<const u32*>(eattr)[(size_t)e*16 + j];
  }
  ebf[(size_t)s*16 + j] = w;
}

// ---------------- h = x @ W_in + b_in ----------------
__global__ __launch_bounds__(256) void k_embed(const void* __restrict__ xraw,
                                               const float* __restrict__ Wb, const float* __restrict__ bb,
                                               float* __restrict__ h){
  __shared__ float xs[8*IN_DIM];
  __shared__ float wsm[IN_DIM*HID];
  int isf32 = wave_isf32((const u32*)xraw);
  int tid = threadIdx.x;
  const float4* wp = reinterpret_cast<const float4*>(Wb);
  #pragma unroll
  for (int it=0; it<8; ++it) ((float4*)wsm)[it*256 + tid] = wp[it*256 + tid];
  if (isf32){
    const float4* xp = reinterpret_cast<const float4*>((const float*)xraw + (size_t)blockIdx.x*8*IN_DIM);
    ((float4*)xs)[tid]       = xp[tid];
    ((float4*)xs)[256 + tid] = xp[256 + tid];
  } else {
    const uint4* xp = reinterpret_cast<const uint4*>((const u16*)xraw + (size_t)blockIdx.x*8*IN_DIM);
    bf8_store(&xs[tid*8], xp[tid]);
  }
  __syncthreads();
  int nl = tid >> 5, j = tid & 31;
  float acc = bb[j];
  const float* xr = &xs[nl*IN_DIM];
  #pragma unroll 8
  for (int c=0; c<IN_DIM; ++c) acc += xr[c]*wsm[c*HID + j];
  h[(size_t)(blockIdx.x*8 + nl)*HID + j] = acc;
}

// ---------------- fused q,k,v + uw + bias4 (q stays in LDS) ----------------
// Phase 1 (6 waves): wave w -> matrix m=w>>1, node half=w&1; lane owns cols c0,c1.
// Phase 2 (ALL 6 waves, node-strided): lane owns uw cols c0,c1 (one head);
//   bias4 via 16-lane partial reduce.
__global__ __launch_bounds__(384) void k_qkvuw2(const float* __restrict__ h,
    const float* __restrict__ blob, const float* __restrict__ M2T,
    const float* __restrict__ bvecb, int l,
    float* __restrict__ q, u32* __restrict__ kpk, u32* __restrict__ vpk,
    float* __restrict__ uw, float* __restrict__ bias4){
  __shared__ float qs[64*HO];     // 32 KB
  int tid = threadIdx.x;
  int w = tid >> 6, lane = tid & 63;
  int hh = lane >> 4, t = lane & 15;
  int c0 = hh*32 + 2*t;
  int c1 = c0 + 1;
  {
    int m = w >> 1, half = w & 1;
    const float* Wm = blob + (m==0 ? OFF_WQ : m==1 ? OFF_WK : OFF_WV) + l*HID*HO;
    const float* bm = blob + (m==0 ? OFF_BQ : m==1 ? OFF_BK : OFF_BV) + l*HO;
    float wA[HID], wB[HID];
    #pragma unroll
    for (int c=0; c<HID; ++c){ wA[c] = Wm[c*HO + c0]; wB[c] = Wm[c*HO + c1]; }
    float bA = bm[c0], bB = bm[c1];
    u32* pk = (m==1) ? kpk : vpk;
    int n0 = blockIdx.x*64 + half*32;
    int nend = n0 + 32; if (nend > N_NODES) nend = N_NODES;
    #pragma unroll 2
    for (int n=n0; n<nend; ++n){
      const float4* hp = reinterpret_cast<const float4*>(h + (size_t)n*HID);
      float accA = bA, accB = bB;
      #pragma unroll
      for (int c4=0; c4<8; ++c4){
        float4 hv = hp[c4];
        accA += hv.x*wA[c4*4+0] + hv.y*wA[c4*4+1] + hv.z*wA[c4*4+2] + hv.w*wA[c4*4+3];
        accB += hv.x*wB[c4*4+0] + hv.y*wB[c4*4+1] + hv.z*wB[c4*4+2] + hv.w*wB[c4*4+3];
      }
      if (m==0){
        *reinterpret_cast<float2*>(q + (size_t)n*HO + c0) = make_float2(accA, accB);
        int loc = half*32 + (n - n0);
        qs[loc*HO + c0] = accA;
        qs[loc*HO + c1] = accB;
      } else {
        pk[(size_t)n*64 + lane] = (u32)f2bf(accA) | ((u32)f2bf(accB) << 16);
      }
    }
  }
  __syncthreads();
  {
    const float* M2l = M2T + l*4096;
    float m2A[HID], m2B[HID];
    #pragma unroll
    for (int d=0; d<HID; ++d){
      m2A[d] = M2l[d*HO + c0];
      m2B[d] = M2l[d*HO + c1];
    }
    float bv0 = bvecb[l*HO + c0], bv1 = bvecb[l*HO + c1];
    int nbase = blockIdx.x*64;
    for (int i = w; i < 64; i += 6){
      int n = nbase + i;
      if (n >= N_NODES) break;
      const float* qrow = &qs[i*HO];
      const float4* qh = reinterpret_cast<const float4*>(qrow + hh*32);
      float a0 = 0.f, a1 = 0.f;
      #pragma unroll
      for (int c4=0; c4<8; ++c4){
        float4 v = qh[c4];
        a0 += v.x*m2A[c4*4+0] + v.y*m2A[c4*4+1] + v.z*m2A[c4*4+2] + v.w*m2A[c4*4+3];
        a1 += v.x*m2B[c4*4+0] + v.y*m2B[c4*4+1] + v.z*m2B[c4*4+2] + v.w*m2B[c4*4+3];
      }
      float pb = qrow[c0]*bv0 + qrow[c1]*bv1;
      pb += __shfl_xor(pb, 1);
      pb += __shfl_xor(pb, 2);
      pb += __shfl_xor(pb, 4);
      pb += __shfl_xor(pb, 8);
      *reinterpret_cast<float2*>(uw + (size_t)n*HO + c0) = make_float2(a0, a1);
      if (t == 0) bias4[(size_t)n*HEADS + hh] = pb;
    }
  }
}

// ---------------- fused: alpha + softmax(heads) + aggregate + Wo + residual + LN ----------------
// Lane L: head hh=L>>4, pair t=L&15 -> dims (2t,2t+1) of head hh. 4-edge unroll (R12-proven).
__global__ __launch_bounds__(256) void k_attn_agg(const int* __restrict__ off,
    const int* __restrict__ srcs,
    const float* __restrict__ q, const u32* __restrict__ kpk, const u32* __restrict__ vpk,
    const float* __restrict__ uw, const float* __restrict__ bias4,
    const u32* __restrict__ ebf,
    const float* __restrict__ Wo, const float* __restrict__ bo,
    const float* __restrict__ lng, const float* __restrict__ lnb,
    int l, int last, float* __restrict__ h, float* __restrict__ hout){
  __shared__ float aggs[4][HO];
  int tid = threadIdx.x;
  int wv = tid >> 6;          // wave -> node
  int L  = tid & 63;
  int n = blockIdx.x*4 + wv;
  int hh = L >> 4, t = L & 15;
  int c0 = hh*32 + 2*t;
  int s0 = off[n], s1 = off[n+1];
  float2 qp = *reinterpret_cast<const float2*>(q  + (size_t)n*HO + c0);
  float2 wp = *reinterpret_cast<const float2*>(uw + (size_t)n*HO + c0);
  float4 B = reinterpret_cast<const float4*>(bias4)[n];
  float bg = (hh==0)? B.x : (hh==1)? B.y : (hh==2)? B.z : B.w;
  float acc0=0.f, acc1=0.f;
  auto proc = [&](u32 kw, u32 vw, u32 ew){
    float pa = qp.x*bf_lo(kw) + qp.y*bf_hi(kw) + wp.x*bf_lo(ew) + wp.y*bf_hi(ew);
    pa += __shfl_xor(pa, 1);
    pa += __shfl_xor(pa, 2);
    pa += __shfl_xor(pa, 4);
    pa += __shfl_xor(pa, 8);
    float e = exp2f((pa + bg)*SCL2);
    float ssum = e + __shfl_xor(e, 16);
    ssum += __shfl_xor(ssum, 32);
    float wgt = e * __builtin_amdgcn_rcpf(ssum);
    acc0 += bf_lo(vw)*wgt;
    acc1 += bf_hi(vw)*wgt;
  };
  int s = s0;
  for (; s + 4 <= s1; s += 4){
    int sn0 = srcs[s], sn1 = srcs[s+1], sn2 = srcs[s+2], sn3 = srcs[s+3];
    u32 kw0 = kpk[(size_t)sn0*64 + L], vw0 = vpk[(size_t)sn0*64 + L];
    u32 kw1 = kpk[(size_t)sn1*64 + L], vw1 = vpk[(size_t)sn1*64 + L];
    u32 kw2 = kpk[(size_t)sn2*64 + L], vw2 = vpk[(size_t)sn2*64 + L];
    u32 kw3 = kpk[(size_t)sn3*64 + L], vw3 = vpk[(size_t)sn3*64 + L];
    u32 ew0 = ebf[(size_t)s*16 + t],       ew1 = ebf[(size_t)(s+1)*16 + t];
    u32 ew2 = ebf[(size_t)(s+2)*16 + t],   ew3 = ebf[(size_t)(s+3)*16 + t];
    proc(kw0, vw0, ew0);
    proc(kw1, vw1, ew1);
    proc(kw2, vw2, ew2);
    proc(kw3, vw3, ew3);
  }
  for (; s < s1; ++s){
    int sn = srcs[s];
    proc(kpk[(size_t)sn*64 + L], vpk[(size_t)sn*64 + L], ebf[(size_t)s*16 + t]);
  }
  *reinterpret_cast<float2*>(&aggs[wv][c0]) = make_float2(acc0, acc1);
  __syncthreads();
  if (tid < 128){
    int nl2 = tid >> 5, j = tid & 31;
    int nn = blockIdx.x*4 + nl2;
    const float* Wol = Wo + l*HO*HID;
    float o = bo[l*HID + j];
    #pragma unroll
    for (int i=0; i<HO; ++i) o += aggs[nl2][i] * Wol[i*HID + j];
    o += h[(size_t)nn*HID + j];                       // residual
    float sum = o;
    #pragma unroll
    for (int m=16; m>=1; m>>=1) sum += __shfl_xor(sum, m);
    float mu = sum * (1.f/32.f);
    float dv = o - mu;
    float vs = dv*dv;
    #pragma unroll
    for (int m=16; m>=1; m>>=1) vs += __shfl_xor(vs, m);
    float xn = dv * rsqrtf(vs*(1.f/32.f) + 1e-5f);
    float res = xn * lng[l*HID + j] + lnb[l*HID + j];
    h[(size_t)nn*HID + j] = res;
    if (last) hout[(size_t)nn*HID + j] = res;
  }
}

// ---------------- pooling (one block per graph; computes own gstart prefix) ----------------
__global__ __launch_bounds__(256) void k_pool(const float* __restrict__ h,
                                              const int* __restrict__ gcount, float* __restrict__ pools){
  __shared__ int gc[NG];
  int g = blockIdx.x;
  int tid = threadIdx.x;
  if (tid < NG) gc[tid] = gcount[tid];
  __syncthreads();
  int start = 0;
  for (int g2=0; g2<g; ++g2) start += gc[g2];
  int cnt = gc[g];
  int sub = tid >> 5, j = tid & 31;
  float sum = 0.f, mx = -1e30f, gs = 0.f;
  for (int i = start + sub; i < start + cnt; i += 8){
    float val = h[(size_t)i*HID + j];
    sum += val;
    mx = fmaxf(mx, val);
    gs += val * (1.0f/(1.0f + __expf(-val)));
  }
  __shared__ float ls[8][HID], lm[8][HID], lg[8][HID];
  ls[sub][j]=sum; lm[sub][j]=mx; lg[sub][j]=gs;
  __syncthreads();
  if (tid < HID){
    float S=0.f, M=-1e30f, G=0.f;
    #pragma unroll
    for (int s2=0; s2<8; ++s2){ S+=ls[s2][tid]; M=fmaxf(M,lm[s2][tid]); G+=lg[s2][tid]; }
    float c = (float)((cnt>0)?cnt:1);
    pools[g*96 + tid]      = S/c;
    pools[g*96 + 32 + tid] = M;
    pools[g*96 + 64 + tid] = G/c;
  }
}

// ---------------- head MLP ----------------
__global__ __launch_bounds__(128) void k_head(const float* __restrict__ pools,
    const float* __restrict__ Wo1, const float* __restrict__ bo1,
    const float* __restrict__ Wo2, const float* __restrict__ bo2,
    float* __restrict__ out){
  int g = blockIdx.x, tid = threadIdx.x;
  __shared__ float rep[96], hid[HID];
  if (tid < 96) rep[tid] = pools[g*96 + tid];
  __syncthreads();
  if (tid < HID){
    float s = bo1[tid];
    #pragma unroll
    for (int c=0; c<96; ++c) s += rep[c]*Wo1[c*HID + tid];
    hid[tid] = fmaxf(s, 0.0f);
  }
  __syncthreads();
  float s = bo2[tid];
  #pragma unroll
  for (int j2=0; j2<HID; ++j2) s += hid[j2]*Wo2[j2*OUT_DIM + tid];
  out[g*OUT_DIM + tid] = s;
}

// ---------------- host ----------------
extern "C" void kernel_launch(void* const* d_in, const int* in_sizes, int n_in,
                              void* d_out, int out_size, void* d_ws, size_t ws_size,
                              hipStream_t stream){
  const void* x     = d_in[0];
  const int*  ei    = (const int*)d_in[1];
  const void* eattr = d_in[2];
  const int*  batch = (const int*)d_in[3];
  float* out = (float*)d_out;

  char* p = (char*)d_ws;
  auto take = [&](size_t bytes)->char*{ char* r = p; p += (bytes + 255) & ~(size_t)255; return r; };
  float* h     = (float*)take((size_t)N_NODES*HID*4);
  float* q     = (float*)take((size_t)N_NODES*HO*4);
  u32*   kpk   = (u32*)  take((size_t)N_NODES*64*4);
  u32*   vpk   = (u32*)  take((size_t)N_NODES*64*4);
  float* uw    = (float*)take((size_t)N_NODES*HO*4);
  float* bias4 = (float*)take((size_t)N_NODES*HEADS*4);
  // zeroed block: deg | cursor | gcount (single memset)
  char* zbase  = take((size_t)N_NODES*4 + 256 + (size_t)N_NODES*4 + 256 + NG*4);
  int* deg     = (int*)zbase;
  int* cursor  = (int*)(zbase + (((size_t)N_NODES*4 + 255) & ~(size_t)255));
  int* gcount  = (int*)((char*)cursor + (((size_t)N_NODES*4 + 255) & ~(size_t)255));
  size_t zspan = ((char*)gcount + NG*4) - zbase;
  int* off     = (int*)take((size_t)(N_NODES+1)*4);
  int* srcs    = (int*)take((size_t)N_EDGES*4);
  int* einv    = (int*)take((size_t)N_EDGES*4);
  float* pools = (float*)take(NG*96*4);
  int*   bsum  = (int*)take(NB_SCAN*4);
  int*   bpre  = (int*)take(NB_SCAN*4);
  float* blob  = (float*)take((size_t)TOTAL_W*4);
  float* M2T   = (float*)take((size_t)3*4096*4);
  float* bvecb = (float*)take((size_t)3*HO*4);
  u32*   ebf   = (u32*)  take((size_t)N_EDGES*16*4);
  (void)ws_size; (void)in_sizes; (void)n_in; (void)out_size;

  Ptrs P;
  for (int i=0; i<20; ++i) P.p[i] = d_in[4+i];

  k_prep<<<NB_CVT + 3, 256, 0, stream>>>(P, (const u32*)x, blob, M2T, bvecb);
  hipMemsetAsync(zbase, 0, zspan, stream);
  k_deg <<<N_EDGES/256, 256, 0, stream>>>(ei, deg);
  k_scan_a<<<NB_SCAN, 256, 0, stream>>>(deg, off, bsum, batch, gcount);
  k_scan_b<<<1, 64, 0, stream>>>(bsum, bpre, off);
  k_scan_c<<<NB_SCAN, 256, 0, stream>>>(off, bpre);
  k_fill<<<N_EDGES/256, 256, 0, stream>>>(ei, off, cursor, srcs, einv);
  k_eperm<<<(N_EDGES*16)/256, 256, 0, stream>>>(einv, eattr, (const u32*)x, ebf);
  k_embed<<<N_NODES/8, 256, 0, stream>>>(x, blob+OFF_WIN, blob+OFF_BIN, h);
  for (int l=0; l<3; ++l){
    k_qkvuw2<<<NB_NODE, 384, 0, stream>>>(h, blob, M2T, bvecb, l, q, kpk, vpk, uw, bias4);
    k_attn_agg<<<N_NODES/4, 256, 0, stream>>>(off, srcs, q, kpk, vpk, uw, bias4, ebf,
                                              blob+OFF_WO, blob+OFF_BO, blob+OFF_LNG, blob+OFF_LNB,
                                              l, (l==2)?1:0, h, out + NG*OUT_DIM);
  }
  k_pool<<<NG, 256, 0, stream>>>(h, gcount, pools);
  k_head<<<NG, 128, 0, stream>>>(pools, blob+OFF_WO1, blob+OFF_BO1, blob+OFF_WO2, blob+OFF_BO2, out);
}

// Round 15
// 778.030 us; speedup vs baseline: 1.0956x; 1.0662x over previous
//
#include <hip/hip_runtime.h>
#include <hip/hip_bf16.h>

#define N_NODES 50000
#define N_EDGES 800000
#define IN_DIM 256
#define HID 32
#define HEADS 4
#define HO 128
#define EDGE_DIM 32
#define NG 32
#define OUT_DIM 128
#define SCALE 0.1767766952966369f       // 1/sqrt(32)
#define SCL2  0.2550889021232886f       // SCALE * log2(e)
#define NB_SCAN ((N_NODES + 255) / 256)   // 196
#define NB_NODE ((N_NODES + 63) / 64)     // 782
#define NB_CVT  312                        // ceil(TOTAL_W/256)
#define NB_DEG  (N_EDGES/256)              // 3125

typedef unsigned short u16;
typedef unsigned int u32;

__device__ __forceinline__ float bf_lo(u32 w){ union{u32 i; float f;} c; c.i=w<<16; return c.f; }
__device__ __forceinline__ float bf_hi(u32 w){ union{u32 i; float f;} c; c.i=w&0xffff0000u; return c.f; }
__device__ __forceinline__ float bf2f(u16 u){ union{u32 i; float f;} c; c.i=((u32)u)<<16; return c.f; }
__device__ __forceinline__ u16 f2bf(float f){ u32 b = __float_as_uint(f); u32 r = (b + 0x7fffu + ((b>>16)&1u)) >> 16; return (u16)r; }
__device__ __forceinline__ void bf8_store(float* d, uint4 w){
  d[0]=bf_lo(w.x); d[1]=bf_hi(w.x); d[2]=bf_lo(w.y); d[3]=bf_hi(w.y);
  d[4]=bf_lo(w.z); d[5]=bf_hi(w.z); d[6]=bf_lo(w.w); d[7]=bf_hi(w.w);
}

// per-wave dtype flag: 1 = f32 inputs, 0 = bf16-pair inputs  (x is N(0,1))
__device__ __forceinline__ int wave_isf32(const u32* __restrict__ xw){
  u32 w = xw[threadIdx.x & 63];
  int e_hi = (w >> 23) & 0xFF;
  int e_lo = (w >> 7) & 0xFF;
  bool pair = (e_hi >= 110 && e_hi <= 140) && (e_lo >= 110 && e_lo <= 140);
  return (__popcll(__ballot(pair)) >= 32) ? 0 : 1;
}

// ---------------- weight blob offsets ----------------
#define OFF_WIN   0
#define OFF_BIN   8192
#define OFF_WEP   8224
#define OFF_BEP   9248
#define OFF_WQ    9280
#define OFF_BQ    21568
#define OFF_WK    21952
#define OFF_BK    34240
#define OFF_WV    34624
#define OFF_BV    46912
#define OFF_WE    47296
#define OFF_BE    59584
#define OFF_WO    59968
#define OFF_BO    72256
#define OFF_LNG   72352
#define OFF_LNB   72448
#define OFF_WO1   72544
#define OFF_BO1   75616
#define OFF_WO2   75648
#define OFF_BO2   79744
#define TOTAL_W   79872

struct Ptrs { const void* p[20]; };

// ---- fused: weight convert [0..NB_CVT) + fold [NB_CVT..NB_CVT+3) + degree count [NB_CVT+3..) ----
__global__ __launch_bounds__(256) void k_prep(Ptrs P, const u32* __restrict__ xw,
                                              const int* __restrict__ ei, int* __restrict__ deg,
                                              float* __restrict__ blob,
                                              float* __restrict__ M2T, float* __restrict__ bvecb){
  int b = blockIdx.x;
  if (b >= NB_CVT + 3){            // degree count (deg pre-zeroed)
    int e = (b - NB_CVT - 3)*256 + threadIdx.x;
    atomicAdd(&deg[ei[N_EDGES + e]], 1);
    return;
  }
  int isf32 = wave_isf32(xw);
  if (b < NB_CVT){
    const int offs[21] = {OFF_WIN,OFF_BIN,OFF_WEP,OFF_BEP,OFF_WQ,OFF_BQ,OFF_WK,OFF_BK,
                          OFF_WV,OFF_BV,OFF_WE,OFF_BE,OFF_WO,OFF_BO,OFF_LNG,OFF_LNB,
                          OFF_WO1,OFF_BO1,OFF_WO2,OFF_BO2,TOTAL_W};
    int i = b*256 + threadIdx.x;
    if (i >= TOTAL_W) return;
    int t = 0;
    while (i >= offs[t+1]) ++t;
    int j = i - offs[t];
    blob[i] = isf32 ? ((const float*)P.p[t])[j] : bf2f(((const u16*)P.p[t])[j]);
  } else {
    int l = b - NB_CVT;
    const void* We  = P.p[10];
    const void* Wep = P.p[2];
    const void* be  = P.p[11];
    const void* bep = P.p[3];
    auto ld = [&](const void* q2, int idx)->float{
      return isf32 ? ((const float*)q2)[idx] : bf2f(((const u16*)q2)[idx]);
    };
    int t = threadIdx.x;
    for (int e = t; e < 4096; e += 256){
      int d = e >> 7, o = e & 127;
      int j = o & 31, hh = o >> 5;
      float s = 0.f;
      #pragma unroll
      for (int c=0; c<32; ++c) s += ld(Wep, j*32 + c) * ld(We, l*HID*HO + c*HO + hh*32 + d);
      M2T[l*4096 + e] = s;
    }
    if (t < HO){
      float s = ld(be, l*HO + t);
      #pragma unroll
      for (int c=0; c<32; ++c) s += ld(bep, c) * ld(We, l*HID*HO + c*HO + t);
      bvecb[l*HO + t] = s;
    }
  }
}

// block scan over deg + group histogram (same node range)  [G12]
__global__ __launch_bounds__(256) void k_scan_a(const int* __restrict__ deg, int* __restrict__ off,
                                                int* __restrict__ bsum,
                                                const int* __restrict__ batch, int* __restrict__ gcount){
  __shared__ int wsum[4];
  __shared__ int hist[NG];
  int tid = threadIdx.x;
  if (tid < NG) hist[tid] = 0;
  int i = blockIdx.x*256 + tid;
  int d = (i < N_NODES) ? deg[i] : 0;
  int lane = tid & 63, w = tid >> 6;
  int incl = d;
  #pragma unroll
  for (int sh=1; sh<64; sh<<=1){
    int t = __shfl_up(incl, sh, 64);
    if (lane >= sh) incl += t;
  }
  if (lane == 63) wsum[w] = incl;
  __syncthreads();     // wsum ready, hist zeroed
  int wpre = 0;
  #pragma unroll
  for (int ww=0; ww<4; ++ww) wpre += (ww < w) ? wsum[ww] : 0;
  if (i < N_NODES) off[i] = wpre + incl - d;
  if (tid == 255) bsum[blockIdx.x] = wpre + incl;
  if (i < N_NODES) atomicAdd(&hist[batch[i]], 1);
  __syncthreads();
  if (tid < NG){
    int c = hist[tid];
    if (c) atomicAdd(&gcount[tid], c);
  }
}

__global__ void k_scan_b(const int* __restrict__ bsum, int* __restrict__ bpre, int* __restrict__ off){
  int lane = threadIdx.x;    // 64
  int carry = 0;
  for (int base=0; base<NB_SCAN; base+=64){
    int i = base + lane;
    int d = (i<NB_SCAN)? bsum[i] : 0;
    int incl = d;
    #pragma unroll
    for (int sh=1; sh<64; sh<<=1){
      int t = __shfl_up(incl, sh, 64);
      if (lane >= sh) incl += t;
    }
    if (i<NB_SCAN) bpre[i] = carry + incl - d;
    carry += __shfl(incl, 63, 64);
  }
  if (lane==0) off[N_NODES] = carry;
}

__global__ __launch_bounds__(256) void k_scan_c(int* __restrict__ off, const int* __restrict__ bpre){
  int i = blockIdx.x*256 + threadIdx.x;
  if (i < N_NODES) off[i] += bpre[blockIdx.x];
}

// slot computation; srcs + inverse permutation einv (both L2-resident scatters)
__global__ void k_fill(const int* __restrict__ ei, const int* __restrict__ off,
                       int* __restrict__ cursor, int* __restrict__ srcs, int* __restrict__ einv){
  int e = blockIdx.x*256 + threadIdx.x;
  int dst = ei[N_EDGES + e];
  int pos = atomicAdd(&cursor[dst], 1);
  int sl = off[dst] + pos;
  srcs[sl] = ei[e];
  einv[sl] = e;
}

// permute eattr into CSR order (gather by slot): random 128B-line reads, streaming writes
__global__ __launch_bounds__(256) void k_eperm(const int* __restrict__ einv, const void* __restrict__ eattr,
                                               const u32* __restrict__ xw, u32* __restrict__ ebf){
  int isf32 = wave_isf32(xw);
  int tid = blockIdx.x*256 + threadIdx.x;   // over N_EDGES*16
  int s = tid >> 4, j = tid & 15;
  int e = einv[s];
  u32 w;
  if (isf32){
    float2 v2 = reinterpret_cast<const float2*>(eattr)[(size_t)e*16 + j];
    w = (u32)f2bf(v2.x) | ((u32)f2bf(v2.y) << 16);
  } else {
    w = reinterpret_cast<const u32*>(eattr)[(size_t)e*16 + j];
  }
  ebf[(size_t)s*16 + j] = w;
}

// ---------------- h = x @ W_in + b_in ----------------
__global__ __launch_bounds__(256) void k_embed(const void* __restrict__ xraw,
                                               const float* __restrict__ Wb, const float* __restrict__ bb,
                                               float* __restrict__ h){
  __shared__ float xs[8*IN_DIM];
  __shared__ float wsm[IN_DIM*HID];
  int isf32 = wave_isf32((const u32*)xraw);
  int tid = threadIdx.x;
  const float4* wp = reinterpret_cast<const float4*>(Wb);
  #pragma unroll
  for (int it=0; it<8; ++it) ((float4*)wsm)[it*256 + tid] = wp[it*256 + tid];
  if (isf32){
    const float4* xp = reinterpret_cast<const float4*>((const float*)xraw + (size_t)blockIdx.x*8*IN_DIM);
    ((float4*)xs)[tid]       = xp[tid];
    ((float4*)xs)[256 + tid] = xp[256 + tid];
  } else {
    const uint4* xp = reinterpret_cast<const uint4*>((const u16*)xraw + (size_t)blockIdx.x*8*IN_DIM);
    bf8_store(&xs[tid*8], xp[tid]);
  }
  __syncthreads();
  int nl = tid >> 5, j = tid & 31;
  float acc = bb[j];
  const float* xr = &xs[nl*IN_DIM];
  #pragma unroll 8
  for (int c=0; c<IN_DIM; ++c) acc += xr[c]*wsm[c*HID + j];
  h[(size_t)(blockIdx.x*8 + nl)*HID + j] = acc;
}

// ---------------- fused q,k,v + uw + bias4 (h-tile and q staged in LDS) ----------------
// Stage 0: all 384 threads cooperatively load the block's 64x32 h-tile into LDS (coalesced).
// Phase 1 (6 waves): wave w -> matrix m=w>>1, node half=w&1; lane owns cols c0,c1; h from LDS.
// Phase 2 (all 6 waves, node-strided): lane owns uw cols c0,c1; bias4 via 16-lane reduce.
__global__ __launch_bounds__(384) void k_qkvuw2(const float* __restrict__ h,
    const float* __restrict__ blob, const float* __restrict__ M2T,
    const float* __restrict__ bvecb, int l,
    float* __restrict__ q, u32* __restrict__ kpk, u32* __restrict__ vpk,
    float* __restrict__ uw, float* __restrict__ bias4){
  __shared__ float hs[64*HID];    // 8 KB
  __shared__ float qs[64*HO];     // 32 KB
  int tid = threadIdx.x;
  int w = tid >> 6, lane = tid & 63;
  int hh = lane >> 4, t = lane & 15;
  int c0 = hh*32 + 2*t;
  int c1 = c0 + 1;
  {
    int nbase = blockIdx.x*64;
    const float4* hsrc = reinterpret_cast<const float4*>(h + (size_t)nbase*HID);
    #pragma unroll
    for (int it=0; it<2; ++it){
      int i = it*384 + tid;       // 512 float4 entries total
      if (i < 512){
        int row = i >> 3;
        float4 v = (nbase + row < N_NODES) ? hsrc[i] : make_float4(0.f,0.f,0.f,0.f);
        reinterpret_cast<float4*>(hs)[i] = v;
      }
    }
  }
  __syncthreads();
  {
    int m = w >> 1, half = w & 1;
    const float* Wm = blob + (m==0 ? OFF_WQ : m==1 ? OFF_WK : OFF_WV) + l*HID*HO;
    const float* bm = blob + (m==0 ? OFF_BQ : m==1 ? OFF_BK : OFF_BV) + l*HO;
    float wA[HID], wB[HID];
    #pragma unroll
    for (int c=0; c<HID; ++c){ wA[c] = Wm[c*HO + c0]; wB[c] = Wm[c*HO + c1]; }
    float bA = bm[c0], bB = bm[c1];
    u32* pk = (m==1) ? kpk : vpk;
    int n0 = blockIdx.x*64 + half*32;
    int nend = n0 + 32; if (nend > N_NODES) nend = N_NODES;
    #pragma unroll 2
    for (int n=n0; n<nend; ++n){
      int loc = half*32 + (n - n0);
      const float4* hp = reinterpret_cast<const float4*>(&hs[loc*HID]);
      float accA = bA, accB = bB;
      #pragma unroll
      for (int c4=0; c4<8; ++c4){
        float4 hv = hp[c4];
        accA += hv.x*wA[c4*4+0] + hv.y*wA[c4*4+1] + hv.z*wA[c4*4+2] + hv.w*wA[c4*4+3];
        accB += hv.x*wB[c4*4+0] + hv.y*wB[c4*4+1] + hv.z*wB[c4*4+2] + hv.w*wB[c4*4+3];
      }
      if (m==0){
        *reinterpret_cast<float2*>(q + (size_t)n*HO + c0) = make_float2(accA, accB);
        qs[loc*HO + c0] = accA;
        qs[loc*HO + c1] = accB;
      } else {
        pk[(size_t)n*64 + lane] = (u32)f2bf(accA) | ((u32)f2bf(accB) << 16);
      }
    }
  }
  __syncthreads();
  {
    const float* M2l = M2T + l*4096;
    float m2A[HID], m2B[HID];
    #pragma unroll
    for (int d=0; d<HID; ++d){
      m2A[d] = M2l[d*HO + c0];
      m2B[d] = M2l[d*HO + c1];
    }
    float bv0 = bvecb[l*HO + c0], bv1 = bvecb[l*HO + c1];
    int nbase = blockIdx.x*64;
    for (int i = w; i < 64; i += 6){
      int n = nbase + i;
      if (n >= N_NODES) break;
      const float* qrow = &qs[i*HO];
      const float4* qh = reinterpret_cast<const float4*>(qrow + hh*32);
      float a0 = 0.f, a1 = 0.f;
      #pragma unroll
      for (int c4=0; c4<8; ++c4){
        float4 v = qh[c4];
        a0 += v.x*m2A[c4*4+0] + v.y*m2A[c4*4+1] + v.z*m2A[c4*4+2] + v.w*m2A[c4*4+3];
        a1 += v.x*m2B[c4*4+0] + v.y*m2B[c4*4+1] + v.z*m2B[c4*4+2] + v.w*m2B[c4*4+3];
      }
      float pb = qrow[c0]*bv0 + qrow[c1]*bv1;
      pb += __shfl_xor(pb, 1);
      pb += __shfl_xor(pb, 2);
      pb += __shfl_xor(pb, 4);
      pb += __shfl_xor(pb, 8);
      *reinterpret_cast<float2*>(uw + (size_t)n*HO + c0) = make_float2(a0, a1);
      if (t == 0) bias4[(size_t)n*HEADS + hh] = pb;
    }
  }
}

// ---------------- fused: alpha + softmax(heads) + aggregate + Wo + residual + LN ----------------
// Lane L: head hh=L>>4, pair t=L&15 -> dims (2t,2t+1) of head hh. 4-edge unroll (R12-proven).
__global__ __launch_bounds__(256) void k_attn_agg(const int* __restrict__ off,
    const int* __restrict__ srcs,
    const float* __restrict__ q, const u32* __restrict__ kpk, const u32* __restrict__ vpk,
    const float* __restrict__ uw, const float* __restrict__ bias4,
    const u32* __restrict__ ebf,
    const float* __restrict__ Wo, const float* __restrict__ bo,
    const float* __restrict__ lng, const float* __restrict__ lnb,
    int l, int last, float* __restrict__ h, float* __restrict__ hout){
  __shared__ float aggs[4][HO];
  int tid = threadIdx.x;
  int wv = tid >> 6;          // wave -> node
  int L  = tid & 63;
  int n = blockIdx.x*4 + wv;
  int hh = L >> 4, t = L & 15;
  int c0 = hh*32 + 2*t;
  int s0 = off[n], s1 = off[n+1];
  float2 qp = *reinterpret_cast<const float2*>(q  + (size_t)n*HO + c0);
  float2 wp = *reinterpret_cast<const float2*>(uw + (size_t)n*HO + c0);
  float4 B = reinterpret_cast<const float4*>(bias4)[n];
  float bg = (hh==0)? B.x : (hh==1)? B.y : (hh==2)? B.z : B.w;
  float acc0=0.f, acc1=0.f;
  auto proc = [&](u32 kw, u32 vw, u32 ew){
    float pa = qp.x*bf_lo(kw) + qp.y*bf_hi(kw) + wp.x*bf_lo(ew) + wp.y*bf_hi(ew);
    pa += __shfl_xor(pa, 1);
    pa += __shfl_xor(pa, 2);
    pa += __shfl_xor(pa, 4);
    pa += __shfl_xor(pa, 8);
    float e = exp2f((pa + bg)*SCL2);
    float ssum = e + __shfl_xor(e, 16);
    ssum += __shfl_xor(ssum, 32);
    float wgt = e * __builtin_amdgcn_rcpf(ssum);
    acc0 += bf_lo(vw)*wgt;
    acc1 += bf_hi(vw)*wgt;
  };
  int s = s0;
  for (; s + 4 <= s1; s += 4){
    int sn0 = srcs[s], sn1 = srcs[s+1], sn2 = srcs[s+2], sn3 = srcs[s+3];
    u32 kw0 = kpk[(size_t)sn0*64 + L], vw0 = vpk[(size_t)sn0*64 + L];
    u32 kw1 = kpk[(size_t)sn1*64 + L], vw1 = vpk[(size_t)sn1*64 + L];
    u32 kw2 = kpk[(size_t)sn2*64 + L], vw2 = vpk[(size_t)sn2*64 + L];
    u32 kw3 = kpk[(size_t)sn3*64 + L], vw3 = vpk[(size_t)sn3*64 + L];
    u32 ew0 = ebf[(size_t)s*16 + t],       ew1 = ebf[(size_t)(s+1)*16 + t];
    u32 ew2 = ebf[(size_t)(s+2)*16 + t],   ew3 = ebf[(size_t)(s+3)*16 + t];
    proc(kw0, vw0, ew0);
    proc(kw1, vw1, ew1);
    proc(kw2, vw2, ew2);
    proc(kw3, vw3, ew3);
  }
  for (; s < s1; ++s){
    int sn = srcs[s];
    proc(kpk[(size_t)sn*64 + L], vpk[(size_t)sn*64 + L], ebf[(size_t)s*16 + t]);
  }
  *reinterpret_cast<float2*>(&aggs[wv][c0]) = make_float2(acc0, acc1);
  __syncthreads();
  if (tid < 128){
    int nl2 = tid >> 5, j = tid & 31;
    int nn = blockIdx.x*4 + nl2;
    const float* Wol = Wo + l*HO*HID;
    float o = bo[l*HID + j];
    #pragma unroll
    for (int i=0; i<HO; ++i) o += aggs[nl2][i] * Wol[i*HID + j];
    o += h[(size_t)nn*HID + j];                       // residual
    float sum = o;
    #pragma unroll
    for (int m=16; m>=1; m>>=1) sum += __shfl_xor(sum, m);
    float mu = sum * (1.f/32.f);
    float dv = o - mu;
    float vs = dv*dv;
    #pragma unroll
    for (int m=16; m>=1; m>>=1) vs += __shfl_xor(vs, m);
    float xn = dv * rsqrtf(vs*(1.f/32.f) + 1e-5f);
    float res = xn * lng[l*HID + j] + lnb[l*HID + j];
    h[(size_t)nn*HID + j] = res;
    if (last) hout[(size_t)nn*HID + j] = res;
  }
}

// ---------------- fused pooling + head MLP (block g handles graph g end-to-end) ----------------
__global__ __launch_bounds__(256) void k_poolhead(const float* __restrict__ h,
    const int* __restrict__ gcount,
    const float* __restrict__ Wo1, const float* __restrict__ bo1,
    const float* __restrict__ Wo2, const float* __restrict__ bo2,
    float* __restrict__ out){
  __shared__ int gc[NG];
  __shared__ float rep[96];
  __shared__ float hid[HID];
  __shared__ float ls[8][HID], lm[8][HID], lg[8][HID];
  int g = blockIdx.x;
  int tid = threadIdx.x;
  if (tid < NG) gc[tid] = gcount[tid];
  __syncthreads();
  int start = 0;
  for (int g2=0; g2<g; ++g2) start += gc[g2];
  int cnt = gc[g];
  int sub = tid >> 5, j = tid & 31;
  float sum = 0.f, mx = -1e30f, gs = 0.f;
  for (int i = start + sub; i < start + cnt; i += 8){
    float val = h[(size_t)i*HID + j];
    sum += val;
    mx = fmaxf(mx, val);
    gs += val * (1.0f/(1.0f + __expf(-val)));
  }
  ls[sub][j]=sum; lm[sub][j]=mx; lg[sub][j]=gs;
  __syncthreads();
  if (tid < HID){
    float S=0.f, M=-1e30f, G=0.f;
    #pragma unroll
    for (int s2=0; s2<8; ++s2){ S+=ls[s2][tid]; M=fmaxf(M,lm[s2][tid]); G+=lg[s2][tid]; }
    float c = (float)((cnt>0)?cnt:1);
    rep[tid]      = S/c;
    rep[32 + tid] = M;
    rep[64 + tid] = G/c;
  }
  __syncthreads();
  if (tid < HID){
    float s = bo1[tid];
    #pragma unroll
    for (int c=0; c<96; ++c) s += rep[c]*Wo1[c*HID + tid];
    hid[tid] = fmaxf(s, 0.0f);
  }
  __syncthreads();
  if (tid < OUT_DIM){
    float s = bo2[tid];
    #pragma unroll
    for (int j2=0; j2<HID; ++j2) s += hid[j2]*Wo2[j2*OUT_DIM + tid];
    out[g*OUT_DIM + tid] = s;
  }
}

// ---------------- host ----------------
extern "C" void kernel_launch(void* const* d_in, const int* in_sizes, int n_in,
                              void* d_out, int out_size, void* d_ws, size_t ws_size,
                              hipStream_t stream){
  const void* x     = d_in[0];
  const int*  ei    = (const int*)d_in[1];
  const void* eattr = d_in[2];
  const int*  batch = (const int*)d_in[3];
  float* out = (float*)d_out;

  char* p = (char*)d_ws;
  auto take = [&](size_t bytes)->char*{ char* r = p; p += (bytes + 255) & ~(size_t)255; return r; };
  float* h     = (float*)take((size_t)N_NODES*HID*4);
  float* q     = (float*)take((size_t)N_NODES*HO*4);
  u32*   kpk   = (u32*)  take((size_t)N_NODES*64*4);
  u32*   vpk   = (u32*)  take((size_t)N_NODES*64*4);
  float* uw    = (float*)take((size_t)N_NODES*HO*4);
  float* bias4 = (float*)take((size_t)N_NODES*HEADS*4);
  // zeroed block: deg | cursor | gcount (single memset)
  char* zbase  = take((size_t)N_NODES*4 + 256 + (size_t)N_NODES*4 + 256 + NG*4);
  int* deg     = (int*)zbase;
  int* cursor  = (int*)(zbase + (((size_t)N_NODES*4 + 255) & ~(size_t)255));
  int* gcount  = (int*)((char*)cursor + (((size_t)N_NODES*4 + 255) & ~(size_t)255));
  size_t zspan = ((char*)gcount + NG*4) - zbase;
  int* off     = (int*)take((size_t)(N_NODES+1)*4);
  int* srcs    = (int*)take((size_t)N_EDGES*4);
  int* einv    = (int*)take((size_t)N_EDGES*4);
  int*   bsum  = (int*)take(NB_SCAN*4);
  int*   bpre  = (int*)take(NB_SCAN*4);
  float* blob  = (float*)take((size_t)TOTAL_W*4);
  float* M2T   = (float*)take((size_t)3*4096*4);
  float* bvecb = (float*)take((size_t)3*HO*4);
  u32*   ebf   = (u32*)  take((size_t)N_EDGES*16*4);
  (void)ws_size; (void)in_sizes; (void)n_in; (void)out_size;

  Ptrs P;
  for (int i=0; i<20; ++i) P.p[i] = d_in[4+i];

  hipMemsetAsync(zbase, 0, zspan, stream);
  k_prep<<<NB_CVT + 3 + NB_DEG, 256, 0, stream>>>(P, (const u32*)x, ei, deg, blob, M2T, bvecb);
  k_scan_a<<<NB_SCAN, 256, 0, stream>>>(deg, off, bsum, batch, gcount);
  k_scan_b<<<1, 64, 0, stream>>>(bsum, bpre, off);
  k_scan_c<<<NB_SCAN, 256, 0, stream>>>(off, bpre);
  k_fill<<<N_EDGES/256, 256, 0, stream>>>(ei, off, cursor, srcs, einv);
  k_eperm<<<(N_EDGES*16)/256, 256, 0, stream>>>(einv, eattr, (const u32*)x, ebf);
  k_embed<<<N_NODES/8, 256, 0, stream>>>(x, blob+OFF_WIN, blob+OFF_BIN, h);
  for (int l=0; l<3; ++l){
    k_qkvuw2<<<NB_NODE, 384, 0, stream>>>(h, blob, M2T, bvecb, l, q, kpk, vpk, uw, bias4);
    k_attn_agg<<<N_NODES/4, 256, 0, stream>>>(off, srcs, q, kpk, vpk, uw, bias4, ebf,
                                              blob+OFF_WO, blob+OFF_BO, blob+OFF_LNG, blob+OFF_LNB,
                                              l, (l==2)?1:0, h, out + NG*OUT_DIM);
  }
  k_poolhead<<<NG, 256, 0, stream>>>(h, gcount, blob+OFF_WO1, blob+OFF_BO1,
                                     blob+OFF_WO2, blob+OFF_BO2, out);
}